// Round 8
// baseline (123.056 us; speedup 1.0000x reference)
//
#include <hip/hip_runtime.h>
#include <hip/hip_bf16.h>

#define BB 16
#define SS 2048
#define DD 1024
#define HH 16
#define KK 31
#define HK 496

typedef float f32x16 __attribute__((ext_vector_type(16)));
typedef float f32x4 __attribute__((ext_vector_type(4)));
typedef __bf16 bf16x8 __attribute__((ext_vector_type(8)));

__device__ __forceinline__ unsigned f2bf(float x) {
  unsigned u = __float_as_uint(x);
  unsigned r = u + 0x7FFFu + ((u >> 16) & 1u);
  return r >> 16;
}

// ---------------- prep: W_q (f32, D x 496) -> bf16 fragment image, N padded 512.
// Bimg[nb][ks][slice][h8][lane][e] = W[k][col]
//   k = ks*32 + slice*16 + (lane>>5)*8 + e, col = (nb*8+h8)*32 + (lane&31)
__global__ void prep_kernel(const float* __restrict__ Wq,
                            unsigned short* __restrict__ Bimg) {
  int idx = blockIdx.x * 256 + threadIdx.x;  // < 2^19
  int e = idx & 7;
  int lane = (idx >> 3) & 63;
  int h8 = (idx >> 9) & 7;
  int s = (idx >> 12) & 1;
  int ks = (idx >> 13) & 31;
  int nb = (idx >> 18) & 1;
  int k = ks * 32 + s * 16 + (lane >> 5) * 8 + e;
  int h = nb * 8 + h8;
  int j = lane & 31;
  float v = (j < KK) ? Wq[k * HK + h * KK + j] : 0.f;
  Bimg[idx] = (unsigned short)f2bf(v);
}

// ---------------- ksum: (B,S,H) = sum over 64 channels per head, f32
__global__ void ksum_kernel(const float* __restrict__ key,
                            float* __restrict__ ksum) {
  const int row = blockIdx.x;
  const int tid = threadIdx.x;
  const f32x4 v = __builtin_nontemporal_load(
      reinterpret_cast<const f32x4*>(key + (size_t)row * DD) + tid);
  float p = v.x + v.y + v.z + v.w;
  p += __shfl_xor(p, 1);
  p += __shfl_xor(p, 2);
  p += __shfl_xor(p, 4);
  p += __shfl_xor(p, 8);
  if ((tid & 15) == 0) ksum[(size_t)row * HH + (tid >> 4)] = p;
}

// ---------------- fused GEMM (32x32x16 bf16) + conv + transpose
// BM=64, BN=256 (8 heads, 1 head/wave), grid 1024, 8 waves.
// A: 8-K-step panels (32KB) double-buffered, loads issued a panel ahead.
// B: global->VGPR, 4-step-deep register prefetch; never drains in the loop.
// Barriers: one lgkm-only s_barrier per panel (4 in the whole K-loop).
__global__ __launch_bounds__(512, 4) void mca_kernel(
    const float* __restrict__ q, const float* __restrict__ bq,
    const float* __restrict__ convb, const float* __restrict__ ksum,
    const unsigned short* __restrict__ Bimg, float* __restrict__ out) {
  extern __shared__ char smem[];
  const int tid = threadIdx.x;
  const int w = tid >> 6, lane = tid & 63;
  const int l31 = lane & 31, hi = lane >> 5;
  const int bid = blockIdx.x;
  const int nb = bid & 1;
  const int mb = bid >> 1;
  const int bb = mb >> 5;
  const int t0 = (mb & 31) << 6;

  char* const buf0 = smem;            // 32KB panel buffer
  char* const buf1 = smem + 32768;    // 32KB panel buffer

  const float* qblk = q + ((size_t)(bb * SS + t0)) * DD;
  const unsigned short* bbase = Bimg + (size_t)nb * 262144 + w * 512 + lane * 8;

  f32x16 acc[2];
#pragma unroll
  for (int mt = 0; mt < 2; ++mt)
#pragma unroll
    for (int r = 0; r < 16; ++r) acc[mt][r] = 0.f;

  f32x4 rq[4];

  // panel p covers k in [p*256, p*256+256); per-thread 8 granules in 2 halves
  auto issueA = [&](int p, int hf) {
#pragma unroll
    for (int it = 0; it < 4; ++it) {
      const int gidx = hf * 2048 + it * 512 + tid;
      const int row = gidx >> 6, c16 = gidx & 63;
      rq[it] = *reinterpret_cast<const f32x4*>(qblk + (size_t)row * DD + p * 256 + c16 * 4);
    }
  };
  auto writeA = [&](char* dst, int hf) {
#pragma unroll
    for (int it = 0; it < 4; ++it) {
      const int gidx = hf * 2048 + it * 512 + tid;
      const int row = gidx >> 6, c16 = gidx & 63;
      const int ksl = c16 >> 3, sl = (c16 >> 2) & 1, h2 = (c16 >> 1) & 1, e2 = c16 & 1;
      int byte = ksl * 4096 + sl * 2048 + h2 * 1024 + row * 16 + e2 * 8;
      byte ^= (h2 << 4) ^ (sl << 5) ^ ((ksl & 1) << 6) ^ (((ksl >> 1) & 1) << 7) ^
              (((ksl >> 2) & 1) << 8);
      unsigned u0 = f2bf(rq[it].x) | (f2bf(rq[it].y) << 16);
      unsigned u1 = f2bf(rq[it].z) | (f2bf(rq[it].w) << 16);
      *reinterpret_cast<uint2*>(dst + byte) = make_uint2(u0, u1);
    }
  };

  bf16x8 Bs[4][2];
  auto loadB = [&](int ks, int slot) {
#pragma unroll
    for (int s = 0; s < 2; ++s)
      Bs[slot][s] = *reinterpret_cast<const bf16x8*>(bbase + (size_t)ks * 8192 + s * 4096);
  };
  auto dsA = [&](const char* buf, int ksl, int s, int mt) -> bf16x8 {
    int byte = ksl * 4096 + s * 2048 + hi * 1024 + (mt * 32 + l31) * 16;
    byte ^= (hi << 4) ^ (s << 5) ^ ((ksl & 1) << 6) ^ (((ksl >> 1) & 1) << 7) ^
            (((ksl >> 2) & 1) << 8);
    return *reinterpret_cast<const bf16x8*>(buf + byte);
  };
  auto lbar = [&]() {
    asm volatile("s_waitcnt lgkmcnt(0)" ::: "memory");
    __builtin_amdgcn_s_barrier();
    asm volatile("" ::: "memory");
  };

  // prologue: 4-deep B, panel 0 staged
  loadB(0, 0);
  loadB(1, 1);
  loadB(2, 2);
  loadB(3, 3);
  issueA(0, 0);
  writeA(buf0, 0);
  issueA(0, 1);
  writeA(buf0, 1);
  lbar();

#pragma unroll
  for (int p = 0; p < 4; ++p) {
    char* cur = (p & 1) ? buf1 : buf0;
    char* nxt = (p & 1) ? buf0 : buf1;
    if (p < 3) issueA(p + 1, 0);  // next panel half 0, a full panel early
#pragma unroll
    for (int st = 0; st < 8; ++st) {
      const int ks = p * 8 + st;
      const int slot = ks & 3;
      bf16x8 a00 = dsA(cur, st, 0, 0);
      bf16x8 a10 = dsA(cur, st, 0, 1);
      acc[0] = __builtin_amdgcn_mfma_f32_32x32x16_bf16(a00, Bs[slot][0], acc[0], 0, 0, 0);
      acc[1] = __builtin_amdgcn_mfma_f32_32x32x16_bf16(a10, Bs[slot][0], acc[1], 0, 0, 0);
      bf16x8 a01 = dsA(cur, st, 1, 0);
      bf16x8 a11 = dsA(cur, st, 1, 1);
      acc[0] = __builtin_amdgcn_mfma_f32_32x32x16_bf16(a01, Bs[slot][1], acc[0], 0, 0, 0);
      acc[1] = __builtin_amdgcn_mfma_f32_32x32x16_bf16(a11, Bs[slot][1], acc[1], 0, 0, 0);
      if (ks + 4 < 32) loadB(ks + 4, slot);  // keep 4 steps in flight
      if (st == 3 && p < 3) {
        writeA(nxt, 0);      // half 0 of next panel (other buffer, no barrier)
        issueA(p + 1, 1);    // issue half 1
      }
    }
    if (p < 3) {
      writeA(nxt, 1);
      lbar();  // lgkm only; B prefetches stay in flight
    }
  }

  // ---- epilogue: conv over j (K=31) in f32; wave w owns head nb*8+w ----
  const int h = nb * 8 + w;
  const float bqv = (l31 < KK) ? bq[h * KK + l31] : 0.f;
  const float cbv = convb[h];

  __syncthreads();  // panel buffers dead; reuse smem for ksum slice
  float* kl = reinterpret_cast<float*>(smem);
  for (int i = tid; i < 96 * 8; i += 512) {
    int trow = i >> 3, h8 = i & 7;
    int t = t0 + trow - 15;
    kl[trow * 9 + h8] =
        (t >= 0 && t < SS) ? ksum[((size_t)bb * SS + t) * HH + nb * 8 + h8] : 0.f;
  }
  __syncthreads();

#pragma unroll
  for (int mt = 0; mt < 2; ++mt)
#pragma unroll
    for (int r = 0; r < 16; ++r) {
      const int tl = mt * 32 + (r & 3) + 8 * (r >> 2) + 4 * hi;
      float v = (acc[mt][r] + bqv) * kl[(tl + l31) * 9 + w];
      v += __shfl_xor(v, 1);
      v += __shfl_xor(v, 2);
      v += __shfl_xor(v, 4);
      v += __shfl_xor(v, 8);
      v += __shfl_xor(v, 16);
      if (l31 == r)
        __builtin_nontemporal_store(v + cbv,
                                    out + ((size_t)(bb * HH + h)) * SS + t0 + tl);
    }
}

extern "C" void kernel_launch(void* const* d_in, const int* in_sizes, int n_in,
                              void* d_out, int out_size, void* d_ws, size_t ws_size,
                              hipStream_t stream) {
  const float* q   = (const float*)d_in[0];
  const float* key = (const float*)d_in[1];
  // d_in[2] (values) and d_in[3] (lengths) are unused by the reference
  const float* Wq  = (const float*)d_in[4];
  const float* bq  = (const float*)d_in[5];
  const float* cvb = (const float*)d_in[6];
  float* out = (float*)d_out;

  float* ksum = (float*)d_ws;                                        // 2 MB
  unsigned short* Bimg = (unsigned short*)((char*)d_ws + (2 << 20)); // 1 MB

  hipFuncSetAttribute((const void*)mca_kernel,
                      hipFuncAttributeMaxDynamicSharedMemorySize, 65536);

  prep_kernel<<<2048, 256, 0, stream>>>(Wq, Bimg);
  ksum_kernel<<<BB * SS, 256, 0, stream>>>(key, ksum);
  mca_kernel<<<BB * (SS / 64) * 2, 512, 65536, stream>>>(q, bq, cvb, ksum, Bimg, out);
}

// Round 9
// 97.129 us; speedup vs baseline: 1.2669x; 1.2669x over previous
//
#include <hip/hip_runtime.h>
#include <hip/hip_bf16.h>

#define BB 16
#define SS 2048
#define DD 1024
#define HH 16
#define KK 31
#define HK 496

typedef float f32x16 __attribute__((ext_vector_type(16)));
typedef float f32x4 __attribute__((ext_vector_type(4)));
typedef __bf16 bf16x8 __attribute__((ext_vector_type(8)));

__device__ __forceinline__ unsigned f2bf(float x) {
  unsigned u = __float_as_uint(x);
  unsigned r = u + 0x7FFFu + ((u >> 16) & 1u);
  return r >> 16;
}

__device__ __forceinline__ void gll16(const void* g, void* l) {
  __builtin_amdgcn_global_load_lds(
      (const __attribute__((address_space(1))) unsigned int*)g,
      (__attribute__((address_space(3))) unsigned int*)l, 16, 0, 0);
}

// ---------------- prep: W_q (f32, D x 496) -> bf16 image, padded N=512 (R6).
// Bimg[ks][slice][w][nt][lane][e] = W[k=ks*32+slice*16+(lane>>5)*8+e][col=w*64+nt*32+(lane&31)]
__global__ void prep_kernel(const float* __restrict__ Wq,
                            unsigned short* __restrict__ Bimg) {
  int idx = blockIdx.x * 256 + threadIdx.x;  // < 524288
  int e = idx & 7;
  int lane = (idx >> 3) & 63;
  int nt = (idx >> 9) & 1;
  int w = (idx >> 10) & 7;
  int slice = (idx >> 13) & 1;
  int ks = idx >> 14;
  int k = ks * 32 + slice * 16 + (lane >> 5) * 8 + e;
  int c = w * 64 + nt * 32 + (lane & 31);
  int h = c >> 5, j = c & 31;
  float v = (j < KK) ? Wq[k * HK + h * KK + j] : 0.f;
  Bimg[idx] = (unsigned short)f2bf(v);
}

// ---------------- ksum: (B,S,H), 16 rows per block, deep independent loads
__global__ __launch_bounds__(256) void ksum_kernel(const float* __restrict__ key,
                                                   float* __restrict__ ksum) {
  const int tid = threadIdx.x;
  const int r0 = blockIdx.x * 16;
#pragma unroll 4
  for (int rr = 0; rr < 16; ++rr) {
    const int row = r0 + rr;
    const f32x4 v = *((const f32x4*)(key + (size_t)row * DD) + tid);
    float p = v.x + v.y + v.z + v.w;
    p += __shfl_xor(p, 1);
    p += __shfl_xor(p, 2);
    p += __shfl_xor(p, 4);
    p += __shfl_xor(p, 8);
    if ((tid & 15) == 0) ksum[(size_t)row * HH + (tid >> 4)] = p;
  }
}

// ---------------- fused GEMM (32x32x16 bf16) + conv + transpose
// BM=64, BN=512, BK=32. A (f32 raw) and B (bf16 image) BOTH staged via
// global_load_lds, double-buffered per K-step. Zero VMEM-to-VGPR loads in
// the K-loop -> one counted vmcnt(5) per step; stage for step k+2 always in
// flight across the whole of step k+1. LDS 80KB -> 2 blocks/CU.
__global__ __launch_bounds__(512, 4) void mca_kernel(
    const float* __restrict__ q, const float* __restrict__ bq,
    const float* __restrict__ convb, const float* __restrict__ ksum,
    const unsigned short* __restrict__ Bimg, float* __restrict__ out) {
  extern __shared__ char smem[];
  const int tid = threadIdx.x;
  const int w = tid >> 6, lane = tid & 63;
  const int l31 = lane & 31, hi = lane >> 5;
  const int bid = blockIdx.x;
  const int bb = bid >> 5;
  const int t0 = (bid & 31) << 6;

  char* const A0 = smem;           // 8KB  f32 A-step
  char* const A1 = smem + 8192;    // 8KB
  char* const B0 = smem + 16384;   // 32KB bf16 B-step
  char* const B1 = smem + 49152;   // 32KB

  const float* qblk = q + ((size_t)(bb * SS + t0)) * DD;
  const char* const BimgB = (const char*)Bimg;

  // A staging geometry: thread -> (row = tid>>3, granule c16 = tid&7).
  // LDS linear dest = tid*16; SOURCE granule pre-swizzled: c16 ^ (row&7).
  const int arow = tid >> 3;
  const int ac16 = tid & 7;
  const float* aSrc = qblk + (size_t)arow * DD + ((ac16 ^ (arow & 7)) << 2);

  f32x16 acc[2][2];
#pragma unroll
  for (int mt = 0; mt < 2; ++mt)
#pragma unroll
    for (int nt = 0; nt < 2; ++nt)
#pragma unroll
      for (int r = 0; r < 16; ++r) acc[mt][nt][r] = 0.f;

  auto stage = [&](int ks, bool odd) {
    char* Ad = odd ? A1 : A0;
    char* Bd = odd ? B1 : B0;
    gll16(aSrc + ks * 32, Ad + w * 1024);  // 1 instr: 8KB/block
#pragma unroll
    for (int r = 0; r < 4; ++r)            // 4 instr: 32KB/block linear copy
      gll16(BimgB + (size_t)ks * 32768 + r * 8192 + (size_t)tid * 16,
            Bd + r * 8192 + w * 1024);
  };

  // A fragment: row = mt*32+l31, k = s*16 + hi*8 + e; granules (2u, 2u+1)
  // stored at position ^ (row&7); cvt f32->bf16 via v_cvt_pk_bf16_f32.
  auto afrag = [&](const char* Ad, int s, int mt) -> bf16x8 {
    const int row = mt * 32 + l31;
    const int u = s * 2 + hi;
    const int g0 = (2 * u) ^ (row & 7);
    const int g1 = (2 * u + 1) ^ (row & 7);
    const f32x4 lo = *(const f32x4*)(Ad + row * 128 + g0 * 16);
    const f32x4 hh = *(const f32x4*)(Ad + row * 128 + g1 * 16);
    unsigned p0, p1, p2, p3;
    asm("v_cvt_pk_bf16_f32 %0, %1, %2" : "=v"(p0) : "v"(lo.x), "v"(lo.y));
    asm("v_cvt_pk_bf16_f32 %0, %1, %2" : "=v"(p1) : "v"(lo.z), "v"(lo.w));
    asm("v_cvt_pk_bf16_f32 %0, %1, %2" : "=v"(p2) : "v"(hh.x), "v"(hh.y));
    asm("v_cvt_pk_bf16_f32 %0, %1, %2" : "=v"(p3) : "v"(hh.z), "v"(hh.w));
    union { unsigned u4[4]; bf16x8 b; } cv;
    cv.u4[0] = p0; cv.u4[1] = p1; cv.u4[2] = p2; cv.u4[3] = p3;
    return cv.b;
  };
  auto bfrag = [&](const char* Bd, int s, int nt) -> bf16x8 {
    return *(const bf16x8*)(Bd + s * 16384 + nt * 1024 + w * 2048 + lane * 16);
  };
  auto compute = [&](const char* Ad, const char* Bd) {
#pragma unroll
    for (int s = 0; s < 2; ++s) {
      bf16x8 b0 = bfrag(Bd, s, 0);
      bf16x8 b1 = bfrag(Bd, s, 1);
      bf16x8 a0 = afrag(Ad, s, 0);
      bf16x8 a1 = afrag(Ad, s, 1);
      acc[0][0] = __builtin_amdgcn_mfma_f32_32x32x16_bf16(a0, b0, acc[0][0], 0, 0, 0);
      acc[1][0] = __builtin_amdgcn_mfma_f32_32x32x16_bf16(a1, b0, acc[1][0], 0, 0, 0);
      acc[0][1] = __builtin_amdgcn_mfma_f32_32x32x16_bf16(a0, b1, acc[0][1], 0, 0, 0);
      acc[1][1] = __builtin_amdgcn_mfma_f32_32x32x16_bf16(a1, b1, acc[1][1], 0, 0, 0);
    }
  };

  // prologue: steps 0 and 1 staged; wait step 0 (5 younger in flight)
  stage(0, false);
  stage(1, true);
  asm volatile("s_waitcnt vmcnt(5)" ::: "memory");
  __builtin_amdgcn_sched_barrier(0);
  __builtin_amdgcn_s_barrier();

#pragma unroll 2
  for (int ks = 0; ks < 30; ++ks) {
    const bool odd = ks & 1;
    compute(odd ? A1 : A0, odd ? B1 : B0);
    __builtin_amdgcn_s_barrier();           // all waves done reading this side
    __builtin_amdgcn_sched_barrier(0);
    stage(ks + 2, odd);                     // refill the side just read
    asm volatile("s_waitcnt vmcnt(5)" ::: "memory");  // step ks+1 landed
    __builtin_amdgcn_sched_barrier(0);
    __builtin_amdgcn_s_barrier();           // publish step ks+1
  }
  compute(A0, B0);                          // ks = 30
  asm volatile("s_waitcnt vmcnt(0)" ::: "memory");    // step 31 landed
  __builtin_amdgcn_sched_barrier(0);
  __builtin_amdgcn_s_barrier();
  compute(A1, B1);                          // ks = 31

  // ---- epilogue (R6, verified): conv over j in f32; wave w -> heads w*2+nt
  float bqv[2], cb[2];
#pragma unroll
  for (int nt = 0; nt < 2; ++nt) {
    const int h = w * 2 + nt;
    bqv[nt] = (l31 < KK) ? bq[h * KK + l31] : 0.f;
    cb[nt] = convb[h];
  }

  __syncthreads();  // buffers dead; reuse smem for ksum slice
  float* kl = reinterpret_cast<float*>(smem);
  for (int i = tid; i < 96 * 16; i += 512) {
    int trow = i >> 4, h = i & 15;
    int t = t0 + trow - 15;
    kl[trow * 17 + h] = (t >= 0 && t < SS) ? ksum[((size_t)bb * SS + t) * HH + h] : 0.f;
  }
  __syncthreads();

#pragma unroll
  for (int mt = 0; mt < 2; ++mt)
#pragma unroll
    for (int nt = 0; nt < 2; ++nt) {
      const int h = w * 2 + nt;
#pragma unroll
      for (int r = 0; r < 16; ++r) {
        const int tl = mt * 32 + (r & 3) + 8 * (r >> 2) + 4 * hi;
        float v = (acc[mt][nt][r] + bqv[nt]) * kl[(tl + l31) * 17 + h];
        v += __shfl_xor(v, 1);
        v += __shfl_xor(v, 2);
        v += __shfl_xor(v, 4);
        v += __shfl_xor(v, 8);
        v += __shfl_xor(v, 16);
        if (l31 == r)
          out[((size_t)(bb * HH + h)) * SS + t0 + tl] = v + cb[nt];
      }
    }
}

extern "C" void kernel_launch(void* const* d_in, const int* in_sizes, int n_in,
                              void* d_out, int out_size, void* d_ws, size_t ws_size,
                              hipStream_t stream) {
  const float* q   = (const float*)d_in[0];
  const float* key = (const float*)d_in[1];
  // d_in[2] (values) and d_in[3] (lengths) are unused by the reference
  const float* Wq  = (const float*)d_in[4];
  const float* bq  = (const float*)d_in[5];
  const float* cvb = (const float*)d_in[6];
  float* out = (float*)d_out;

  float* ksum = (float*)d_ws;                                        // 2 MB
  unsigned short* Bimg = (unsigned short*)((char*)d_ws + (2 << 20)); // 1 MB

  hipFuncSetAttribute((const void*)mca_kernel,
                      hipFuncAttributeMaxDynamicSharedMemorySize, 81920);

  prep_kernel<<<2048, 256, 0, stream>>>(Wq, Bimg);
  ksum_kernel<<<2048, 256, 0, stream>>>(key, ksum);
  mca_kernel<<<BB * (SS / 64), 512, 81920, stream>>>(q, bq, cvb, ksum, Bimg, out);
}